// Round 5
// baseline (181.029 us; speedup 1.0000x reference)
//
#include <hip/hip_runtime.h>

#define IN_F 256
#define OUT_F 4096
#define BATCH 8192
#define ROWS_PER_BLOCK 8   // full 16 KiB rows per block; grid = 1024 blocks

typedef float v4f __attribute__((ext_vector_type(4)));

// Kernel 1: recover the one-hot source index per output feature.
// One 64-lane wave per row of expansion_mapping [OUT_F, IN_F].
__global__ __launch_bounds__(256) void urbf_build_idx(
    const float* __restrict__ em, int* __restrict__ idx) {
    const int wave = blockIdx.x * (blockDim.x >> 6) + (threadIdx.x >> 6);
    const int lane = threadIdx.x & 63;
    if (wave >= OUT_F) return;
    const float4 v = *(const float4*)(em + (size_t)wave * IN_F + lane * 4);
    const bool nz = (v.x != 0.0f) | (v.y != 0.0f) | (v.z != 0.0f) | (v.w != 0.0f);
    const unsigned long long m = __ballot(nz);
    const int sub = (v.x != 0.0f) ? 0 : (v.y != 0.0f) ? 1 : (v.z != 0.0f) ? 2 : 3;
    const int src = m ? (int)(__ffsll(m) - 1) : 0;
    const int subs = __shfl(sub, src);
    if (lane == 0) idx[wave] = m ? src * 4 + subs : 0;
}

// Kernel 2: R2 structure (best known: 151.7us) + DIAGNOSTIC mirror stores.
// Each output float4 is additionally stored to a dead workspace region at
// fresh addresses -> +134 MB of GENUINE HBM write bytes that cannot hide in
// L2/MALL (unlike R4's same-address REP, which rode free under the drain).
// Readout is dur_us alone:
//   +~20us  -> main is HBM-byte-saturated; iteration byte-floored -> ROOFLINE
//   +<10us  -> HBM-level slack exists in main's window -> attack overlap
__global__ __launch_bounds__(256) void urbf_main(
    const float* __restrict__ x, const int* __restrict__ idx,
    const float* __restrict__ means, const float* __restrict__ vars_,
    const float* __restrict__ coefs, float* __restrict__ out,
    float* __restrict__ mirror) {
    const int t = threadIdx.x;
    const float C = -0.72134752044448170368f;  // -0.5 * log2(e)

    int    sis[4];
    float4 mu[4], a[4], cc[4];
    bool uniform = true;
    #pragma unroll
    for (int jj = 0; jj < 4; ++jj) {
        const int j = jj * 1024 + t * 4;
        const int4 si = *(const int4*)(idx + j);
        sis[jj] = si.x;
        uniform = uniform & (si.x == si.y) & (si.x == si.z) & (si.x == si.w);
        mu[jj] = *(const float4*)(means + j);
        cc[jj] = *(const float4*)(coefs + j);
        const float4 vv = *(const float4*)(vars_ + j);
        float4 r;
        r.x = __frcp_rn(vv.x); r.y = __frcp_rn(vv.y);
        r.z = __frcp_rn(vv.z); r.w = __frcp_rn(vv.w);
        a[jj].x = C * r.x * r.x; a[jj].y = C * r.y * r.y;
        a[jj].z = C * r.z * r.z; a[jj].w = C * r.w * r.w;
    }

    const int b0 = blockIdx.x * ROWS_PER_BLOCK;
    const float* xb = x + (size_t)b0 * IN_F;
    const size_t obase = (size_t)b0 * OUT_F + t * 4;
    float* ob = out + obase;
    float* mb = mirror ? mirror + obase : nullptr;

    if (uniform) {
        // ---- fast path: one source column per chunk; all loads up front ----
        float xs[ROWS_PER_BLOCK][4];
        #pragma unroll
        for (int r = 0; r < ROWS_PER_BLOCK; ++r) {
            #pragma unroll
            for (int jj = 0; jj < 4; ++jj)
                xs[r][jj] = xb[r * IN_F + sis[jj]];
        }
        #pragma unroll
        for (int r = 0; r < ROWS_PER_BLOCK; ++r) {
            float* op = ob + (size_t)r * OUT_F;
            float* mp = mb ? mb + (size_t)r * OUT_F : nullptr;
            #pragma unroll
            for (int jj = 0; jj < 4; ++jj) {
                const float xv = xs[r][jj];
                v4f o; float d;
                d = xv - mu[jj].x; o.x = __builtin_amdgcn_exp2f(d * d * a[jj].x) * cc[jj].x;
                d = xv - mu[jj].y; o.y = __builtin_amdgcn_exp2f(d * d * a[jj].y) * cc[jj].y;
                d = xv - mu[jj].z; o.z = __builtin_amdgcn_exp2f(d * d * a[jj].z) * cc[jj].z;
                d = xv - mu[jj].w; o.w = __builtin_amdgcn_exp2f(d * d * a[jj].w) * cc[jj].w;
                *(v4f*)(op + jj * 1024) = o;
                if (mp) *(v4f*)(mp + jj * 1024) = o;   // diagnostic HBM bytes
            }
        }
    } else {
        // ---- generic path: arbitrary one-hot rows (4 gathers per chunk) ----
        #pragma unroll
        for (int r = 0; r < ROWS_PER_BLOCK; ++r) {
            const float* xrow = xb + (size_t)r * IN_F;
            float* op = ob + (size_t)r * OUT_F;
            float* mp = mb ? mb + (size_t)r * OUT_F : nullptr;
            #pragma unroll
            for (int jj = 0; jj < 4; ++jj) {
                const int j = jj * 1024 + t * 4;
                const int4 si = *(const int4*)(idx + j);
                v4f o; float d;
                d = xrow[si.x] - mu[jj].x; o.x = __builtin_amdgcn_exp2f(d * d * a[jj].x) * cc[jj].x;
                d = xrow[si.y] - mu[jj].y; o.y = __builtin_amdgcn_exp2f(d * d * a[jj].y) * cc[jj].y;
                d = xrow[si.z] - mu[jj].z; o.z = __builtin_amdgcn_exp2f(d * d * a[jj].z) * cc[jj].z;
                d = xrow[si.w] - mu[jj].w; o.w = __builtin_amdgcn_exp2f(d * d * a[jj].w) * cc[jj].w;
                *(v4f*)(op + jj * 1024) = o;
                if (mp) *(v4f*)(mp + jj * 1024) = o;   // diagnostic HBM bytes
            }
        }
    }
}

extern "C" void kernel_launch(void* const* d_in, const int* in_sizes, int n_in,
                              void* d_out, int out_size, void* d_ws, size_t ws_size,
                              hipStream_t stream) {
    const float* x     = (const float*)d_in[0];   // [BATCH, IN_F]
    const float* em    = (const float*)d_in[1];   // [OUT_F, IN_F]
    const float* means = (const float*)d_in[2];   // [OUT_F]
    const float* vars_ = (const float*)d_in[3];   // [OUT_F]
    const float* coefs = (const float*)d_in[4];   // [OUT_F]
    float* out = (float*)d_out;                   // [BATCH, OUT_F]
    int* idx = (int*)d_ws;                        // 4096 ints = 16 KiB

    // Mirror region for the HBM-byte probe: upper part of the workspace,
    // well clear of the 16 KiB idx region. Needs 134 MB at +192 MiB.
    const size_t MOFF = 192ull << 20;
    const size_t MBYTES = (size_t)BATCH * OUT_F * sizeof(float);   // 134 MB
    float* mirror = (ws_size >= MOFF + MBYTES)
                        ? (float*)((char*)d_ws + MOFF) : nullptr;

    // Kernel 1: 4096 waves, 4 waves/block -> 1024 blocks.
    urbf_build_idx<<<OUT_F / 4, 256, 0, stream>>>(em, idx);

    // Kernel 2: 1024 blocks, each owns 8 full rows (128 KiB contiguous).
    urbf_main<<<BATCH / ROWS_PER_BLOCK, 256, 0, stream>>>(
        x, idx, means, vars_, coefs, out, mirror);
}

// Round 6
// 151.156 us; speedup vs baseline: 1.1976x; 1.1976x over previous
//
#include <hip/hip_runtime.h>

#define IN_F 256
#define OUT_F 4096
#define BATCH 8192
#define ROWS_PER_BLOCK 8   // full 16 KiB rows per block; grid = 1024 blocks

typedef float v4f __attribute__((ext_vector_type(4)));

// Kernel 1: recover the one-hot source index per output feature.
// One 64-lane wave per row of expansion_mapping [OUT_F, IN_F].
// float4 load: the whole 1 KiB row in ONE vector load per wave.
__global__ __launch_bounds__(256) void urbf_build_idx(
    const float* __restrict__ em, int* __restrict__ idx) {
    const int wave = blockIdx.x * (blockDim.x >> 6) + (threadIdx.x >> 6);
    const int lane = threadIdx.x & 63;
    if (wave >= OUT_F) return;
    const float4 v = *(const float4*)(em + (size_t)wave * IN_F + lane * 4);
    const bool nz = (v.x != 0.0f) | (v.y != 0.0f) | (v.z != 0.0f) | (v.w != 0.0f);
    const unsigned long long m = __ballot(nz);
    const int sub = (v.x != 0.0f) ? 0 : (v.y != 0.0f) ? 1 : (v.z != 0.0f) ? 2 : 3;
    const int src = m ? (int)(__ffsll(m) - 1) : 0;
    const int subs = __shfl(sub, src);
    if (lane == 0) idx[wave] = m ? src * 4 + subs : 0;
}

// Kernel 2 — FINAL (R2 structure, best measured: 151.7 us total).
// One block owns ROWS_PER_BLOCK full output rows (contiguous 128 KiB).
// Each thread owns 4 j-chunks (j = jj*1024 + 4*tid), params in registers,
// streams 8 rows; plain dwordx4 stores.
//
// Roofline evidence (R2-R5 probe series):
//  - R2: store-pattern restructure          -> null (not pattern-bound)
//  - R3: nontemporal path + 2x blocks       -> -9us (nt defeats MALL absorb)
//  - R4: REP=2 same-address store replay    -> free (window drain-floored)
//  - R5: +134 MB fresh-address mirror bytes -> +29us (full byte cost:
//        HBM-byte-SATURATED, no overlap slack in main's window)
// Iteration = harness 512 MiB poison fill (~82us, mandatory) + output poison
// + our 134 MB output + ~10 MB reads ~= observed 152us. At the write floor.
__global__ __launch_bounds__(256) void urbf_main(
    const float* __restrict__ x, const int* __restrict__ idx,
    const float* __restrict__ means, const float* __restrict__ vars_,
    const float* __restrict__ coefs, float* __restrict__ out) {
    const int t = threadIdx.x;
    const float C = -0.72134752044448170368f;  // -0.5 * log2(e)

    int    sis[4];
    float4 mu[4], a[4], cc[4];
    bool uniform = true;
    #pragma unroll
    for (int jj = 0; jj < 4; ++jj) {
        const int j = jj * 1024 + t * 4;
        const int4 si = *(const int4*)(idx + j);
        sis[jj] = si.x;
        uniform = uniform & (si.x == si.y) & (si.x == si.z) & (si.x == si.w);
        mu[jj] = *(const float4*)(means + j);
        cc[jj] = *(const float4*)(coefs + j);
        const float4 vv = *(const float4*)(vars_ + j);
        float4 r;
        r.x = __frcp_rn(vv.x); r.y = __frcp_rn(vv.y);
        r.z = __frcp_rn(vv.z); r.w = __frcp_rn(vv.w);
        a[jj].x = C * r.x * r.x; a[jj].y = C * r.y * r.y;
        a[jj].z = C * r.z * r.z; a[jj].w = C * r.w * r.w;
    }

    const int b0 = blockIdx.x * ROWS_PER_BLOCK;
    const float* xb = x + (size_t)b0 * IN_F;
    float* ob = out + (size_t)b0 * OUT_F + t * 4;

    if (uniform) {
        // ---- fast path: one source column per chunk; all loads up front ----
        float xs[ROWS_PER_BLOCK][4];
        #pragma unroll
        for (int r = 0; r < ROWS_PER_BLOCK; ++r) {
            #pragma unroll
            for (int jj = 0; jj < 4; ++jj)
                xs[r][jj] = xb[r * IN_F + sis[jj]];
        }
        #pragma unroll
        for (int r = 0; r < ROWS_PER_BLOCK; ++r) {
            float* op = ob + (size_t)r * OUT_F;
            #pragma unroll
            for (int jj = 0; jj < 4; ++jj) {
                const float xv = xs[r][jj];
                v4f o; float d;
                d = xv - mu[jj].x; o.x = __builtin_amdgcn_exp2f(d * d * a[jj].x) * cc[jj].x;
                d = xv - mu[jj].y; o.y = __builtin_amdgcn_exp2f(d * d * a[jj].y) * cc[jj].y;
                d = xv - mu[jj].z; o.z = __builtin_amdgcn_exp2f(d * d * a[jj].z) * cc[jj].z;
                d = xv - mu[jj].w; o.w = __builtin_amdgcn_exp2f(d * d * a[jj].w) * cc[jj].w;
                *(v4f*)(op + jj * 1024) = o;
            }
        }
    } else {
        // ---- generic path: arbitrary one-hot rows (4 gathers per chunk) ----
        #pragma unroll
        for (int r = 0; r < ROWS_PER_BLOCK; ++r) {
            const float* xrow = xb + (size_t)r * IN_F;
            float* op = ob + (size_t)r * OUT_F;
            #pragma unroll
            for (int jj = 0; jj < 4; ++jj) {
                const int j = jj * 1024 + t * 4;
                const int4 si = *(const int4*)(idx + j);
                v4f o; float d;
                d = xrow[si.x] - mu[jj].x; o.x = __builtin_amdgcn_exp2f(d * d * a[jj].x) * cc[jj].x;
                d = xrow[si.y] - mu[jj].y; o.y = __builtin_amdgcn_exp2f(d * d * a[jj].y) * cc[jj].y;
                d = xrow[si.z] - mu[jj].z; o.z = __builtin_amdgcn_exp2f(d * d * a[jj].z) * cc[jj].z;
                d = xrow[si.w] - mu[jj].w; o.w = __builtin_amdgcn_exp2f(d * d * a[jj].w) * cc[jj].w;
                *(v4f*)(op + jj * 1024) = o;
            }
        }
    }
}

extern "C" void kernel_launch(void* const* d_in, const int* in_sizes, int n_in,
                              void* d_out, int out_size, void* d_ws, size_t ws_size,
                              hipStream_t stream) {
    const float* x     = (const float*)d_in[0];   // [BATCH, IN_F]
    const float* em    = (const float*)d_in[1];   // [OUT_F, IN_F]
    const float* means = (const float*)d_in[2];   // [OUT_F]
    const float* vars_ = (const float*)d_in[3];   // [OUT_F]
    const float* coefs = (const float*)d_in[4];   // [OUT_F]
    float* out = (float*)d_out;                   // [BATCH, OUT_F]
    int* idx = (int*)d_ws;                        // 4096 ints = 16 KiB

    // Kernel 1: 4096 waves, 4 waves/block -> 1024 blocks.
    urbf_build_idx<<<OUT_F / 4, 256, 0, stream>>>(em, idx);

    // Kernel 2: 1024 blocks, each owns 8 full rows (128 KiB contiguous).
    urbf_main<<<BATCH / ROWS_PER_BLOCK, 256, 0, stream>>>(x, idx, means, vars_, coefs, out);
}